// Round 1
// baseline (314.530 us; speedup 1.0000x reference)
//
#include <hip/hip_runtime.h>

// Submanifold sparse conv 3x3x3, G=128, Cin=Cout=32.
// R7: spatial counting-sort (Morton 4^3 buckets) so each 16-pt MFMA tile is
// spatially compact -> neighbor gathers hit L1/L2; table stores -(slot+2)
// (winner-fixup keeps atomicMax duplicate semantics); weights hoisted to
// 108 VGPRs (zero in-loop LDS reads -> no 8-way bank conflicts); XCD-bijective
// block swizzle gives each XCD a contiguous Morton chunk (~its 4MB L2).
// Workspace: table 8MB | wtT 64KB | hist 128KB | keyS 2MB | origId 2MB |
// featsB 32MB  (~42.7 MiB total).

#define GRID 128
#define CIN 32
#define COUT 32
#define NOFF 27
#define NBUCKET 32768   // (128/4)^3

typedef __attribute__((ext_vector_type(8))) short bf16x8;
typedef __attribute__((ext_vector_type(4))) float f32x4;

__device__ inline unsigned short f2bf(float x) {
    union { float f; unsigned u; } v; v.f = x;
    unsigned r = v.u + 0x7fff + ((v.u >> 16) & 1);   // RTNE
    return (unsigned short)(r >> 16);
}

__device__ inline unsigned spread3(unsigned v) {      // 5 bits -> every 3rd bit
    v &= 31u;
    v = (v | (v << 16)) & 0x030000FFu;
    v = (v | (v << 8))  & 0x0300F00Fu;
    v = (v | (v << 4))  & 0x030C30C3u;
    v = (v | (v << 2))  & 0x09249249u;
    return v;
}
__device__ inline int morton_bucket(int x, int y, int z) {
    return (int)(spread3(x >> 2) | (spread3(y >> 2) << 1) | (spread3(z >> 2) << 2));
}

// K1: table scatter (atomicMax, numpy last/max-index-wins), bucket histogram,
// weight transpose [27][ci][co] -> [27][co][ci] bf16.
__global__ void hist_kernel(const int* __restrict__ pos,
                            const float* __restrict__ wt,
                            int* __restrict__ table,
                            int* __restrict__ hist,
                            unsigned short* __restrict__ wtT, int N) {
    int i = blockIdx.x * 256 + threadIdx.x;
    if (i < N) {
        int x = pos[3 * i], y = pos[3 * i + 1], z = pos[3 * i + 2];
        int h = (x * GRID + y) * GRID + z;
        atomicMax(&table[h], i);
        atomicAdd(&hist[morton_bucket(x, y, z)], 1);
    }
    if (i < NOFF * CIN * COUT) {
        int k = i >> 10, r = i & 1023, ci = r >> 5, co = r & 31;
        wtT[k * 1024 + co * 32 + ci] = f2bf(wt[i]);
    }
}

// K2: exclusive scan of 32768 bucket counts; 1 block, 32 values/thread.
__global__ __launch_bounds__(1024) void scan_kernel(int* __restrict__ hist) {
    __shared__ int sums[1024];
    int t = threadIdx.x;
    int base = t * 32;
    int v[32];
#pragma unroll
    for (int j = 0; j < 32; ++j) v[j] = hist[base + j];
    int s = 0;
#pragma unroll
    for (int j = 0; j < 32; ++j) { int tmp = v[j]; v[j] = s; s += tmp; }
    sums[t] = s;
    __syncthreads();
    for (int off = 1; off < 1024; off <<= 1) {
        int add = (t >= off) ? sums[t - off] : 0;
        __syncthreads();
        sums[t] += add;
        __syncthreads();
    }
    int excl = sums[t] - s;   // exclusive prefix of this thread's chunk
#pragma unroll
    for (int j = 0; j < 32; ++j) hist[base + j] = excl + v[j];
}

// K3: assign sorted slots, record key+origId, rewrite table entry of the
// duplicate-winner to -(slot+2). Race-safe: only the single winner of a voxel
// writes its entry; losers compare against a non-negative id and never match
// a negative slot encoding.
__global__ void scatter_kernel(const int* __restrict__ pos,
                               int* __restrict__ hist,
                               int* __restrict__ table,
                               int* __restrict__ keyS,
                               int* __restrict__ origId, int N) {
    int i = blockIdx.x * 256 + threadIdx.x;
    if (i >= N) return;
    int x = pos[3 * i], y = pos[3 * i + 1], z = pos[3 * i + 2];
    int h = (x * GRID + y) * GRID + z;
    int slot = atomicAdd(&hist[morton_bucket(x, y, z)], 1);
    keyS[slot] = h;
    origId[slot] = i;
    if (table[h] == i) table[h] = -(slot + 2);
}

// K4: feats fp32 -> bf16 into SORTED layout. Writes coalesced; reads are
// random 128B row segments (4 consecutive threads cover one row).
__global__ void convert_kernel(const float* __restrict__ feats,
                               const int* __restrict__ origId,
                               uint4* __restrict__ featsB, int N4) {
    int j = blockIdx.x * 256 + threadIdx.x;
    if (j >= N4) return;
    int slot = j >> 2, t = j & 3;
    int o = origId[slot];
    const float4* s = (const float4*)(feats + (size_t)o * CIN + t * 8);
    float4 a = s[0], b = s[1];
    uint4 r;
    r.x = (unsigned)f2bf(a.x) | ((unsigned)f2bf(a.y) << 16);
    r.y = (unsigned)f2bf(a.z) | ((unsigned)f2bf(a.w) << 16);
    r.z = (unsigned)f2bf(b.x) | ((unsigned)f2bf(b.y) << 16);
    r.w = (unsigned)f2bf(b.z) | ((unsigned)f2bf(b.w) << 16);
    featsB[j] = r;
}

// K5: implicit-GEMM conv over sorted slots. Weights live in registers
// (54 x bf16x8 = 108 VGPR); k-loop is gather + 2 MFMA only.
__global__ __launch_bounds__(1024, 8)
void conv_kernel(const unsigned short* __restrict__ featsB,
                 const int* __restrict__ keyS,
                 const unsigned short* __restrict__ wtT,
                 const int* __restrict__ table,
                 const int* __restrict__ origId,
                 float* __restrict__ out, int N) {
    __shared__ __align__(16) unsigned short ldsw[NOFF * 1024]; // 55296 B

    // XCD-bijective swizzle: contiguous Morton chunk per XCD (m204 formula).
    int nwg = (int)gridDim.x;
    int orig = (int)blockIdx.x;
    int q8 = nwg >> 3, r8 = nwg & 7;
    int xcd = orig & 7, lin = orig >> 3;
    int bid = (xcd < r8 ? xcd * (q8 + 1) : r8 * (q8 + 1) + (xcd - r8) * q8) + lin;

    int tid = threadIdx.x;
    int wave = tid >> 6, lane = tid & 63;
    int m = lane & 15, quad = lane >> 4;
    int tile = bid * 16 + wave;
    int base = tile * 16;
    int g = base + m;
    bool gv = g < N;

    int key = gv ? keyS[g] : 0;               // key == hash == (x*128+y)*128+z
    int x = key >> 14, y = (key >> 7) & 127, z = key & 127;
    bool v0[3] = {gv && x > 0, gv, gv && x < GRID - 1};
    bool v1[3] = {gv && y > 0, gv, gv && y < GRID - 1};
    bool v2[3] = {gv && z > 0, gv, gv && z < GRID - 1};

    // Phase A: 27 independent table lookups (MLP), in flight during staging.
    int ids[NOFF];
#pragma unroll
    for (int k = 0; k < NOFF; ++k) {
        const int dx = k / 9, dy = (k / 3) % 3, dz = k % 3;
        bool ok = v0[dx] && v1[dy] && v2[dz];
        int hk = key + (dx - 1) * GRID * GRID + (dy - 1) * GRID + (dz - 1);
        hk = ok ? hk : 0;
        int id = table[hk];
        ids[k] = ok ? id : -1;                // -1 empty, -(slot+2) occupied
    }

    // Stage W^T into LDS (once per block), then hoist to registers (once).
    {
        const uint4* src = (const uint4*)wtT;   // 3456 x 16B
        uint4* dst = (uint4*)ldsw;
        for (int e = tid; e < NOFF * 1024 * 2 / 16; e += 1024) dst[e] = src[e];
    }
    __syncthreads();

    bf16x8 w0[NOFF], w1[NOFF];
    const unsigned short* wb = ldsw + m * 32 + quad * 8;
#pragma unroll
    for (int k = 0; k < NOFF; ++k) {
        w0[k] = *(const bf16x8*)(wb + k * 1024);        // co = m
        w1[k] = *(const bf16x8*)(wb + k * 1024 + 512);  // co = m+16
    }

    f32x4 acc0 = {0.f, 0.f, 0.f, 0.f};
    f32x4 acc1 = {0.f, 0.f, 0.f, 0.f};

    // Phase B: gather + MFMA only; no LDS traffic in the loop.
#pragma unroll
    for (int k = 0; k < NOFF; ++k) {
        int id = ids[k];
        bool val = id < -1;
        int row = val ? (-id - 2) * CIN : 0;            // sorted slot * 32
        bf16x8 a = *(const bf16x8*)(featsB + row + quad * 8);
        if (!val) a = (bf16x8){0, 0, 0, 0, 0, 0, 0, 0};
        acc0 = __builtin_amdgcn_mfma_f32_16x16x32_bf16(a, w0[k], acc0, 0, 0, 0);
        acc1 = __builtin_amdgcn_mfma_f32_16x16x32_bf16(a, w1[k], acc1, 0, 0, 0);
    }

    // D layout: col = lane&15 = co, row = quad*4 + i = slot within tile.
#pragma unroll
    for (int i = 0; i < 4; ++i) {
        int p = base + quad * 4 + i;
        if (p < N) {
            int o = origId[p];
            out[(size_t)o * COUT + m]      = acc0[i];
            out[(size_t)o * COUT + m + 16] = acc1[i];
        }
    }
}

extern "C" void kernel_launch(void* const* d_in, const int* in_sizes, int n_in,
                              void* d_out, int out_size, void* d_ws, size_t ws_size,
                              hipStream_t stream) {
    const float* feats = (const float*)d_in[0];   // [N, 32]
    const int*   pos   = (const int*)d_in[1];     // [N, 3]
    const float* wt    = (const float*)d_in[2];   // [27, 32, 32]
    float* out = (float*)d_out;                   // [N, 32]
    int N = in_sizes[0] / CIN;

    char* ws = (char*)d_ws;
    size_t off = 0;
    int* table = (int*)(ws + off);            off += (size_t)GRID * GRID * GRID * 4; // 8 MB
    unsigned short* wtT = (unsigned short*)(ws + off); off += 65536;                 // 64 KB
    int* hist = (int*)(ws + off);             off += NBUCKET * 4;                    // 128 KB
    int* keyS = (int*)(ws + off);             off += 2097152;                        // 2 MB
    int* origId = (int*)(ws + off);           off += 2097152;                        // 2 MB
    unsigned short* featsB = (unsigned short*)(ws + off);                            // 32 MB

    hipMemsetAsync(table, 0xFF, (size_t)GRID * GRID * GRID * 4, stream);
    hipMemsetAsync(hist, 0, NBUCKET * 4, stream);

    int blocksN = (N + 255) / 256;
    hist_kernel<<<blocksN, 256, 0, stream>>>(pos, wt, table, hist, wtT, N);
    scan_kernel<<<1, 1024, 0, stream>>>(hist);
    scatter_kernel<<<blocksN, 256, 0, stream>>>(pos, hist, table, keyS, origId, N);
    convert_kernel<<<(N * 4 + 255) / 256, 256, 0, stream>>>(feats, origId,
                                                            (uint4*)featsB, N * 4);

    int numTiles = (N + 15) / 16;
    int nwg = (numTiles + 15) / 16;   // 16 waves (1024 threads) per block
    conv_kernel<<<nwg, 1024, 0, stream>>>(featsB, keyS, wtT, table, origId, out, N);
}